// Round 1
// baseline (294.684 us; speedup 1.0000x reference)
//
#include <hip/hip_runtime.h>
#include <math.h>

#define HEADS 12
#define HSZ   64
#define SEQ   512
#define BATCH 16
#define HID   768
#define NOUT  1536      // HEADS*2*HSZ
#define NEGQ  1.25e11f  // 1e12 / 8

typedef _Float16 f16x8 __attribute__((ext_vector_type(8)));
typedef _Float16 f16x4 __attribute__((ext_vector_type(4)));
typedef float    f32x4 __attribute__((ext_vector_type(4)));

__device__ __forceinline__ void async_ld16(const void* g, void* l) {
  __builtin_amdgcn_global_load_lds(
      (__attribute__((address_space(1))) void*)g,
      (__attribute__((address_space(3))) void*)l, 16, 0, 0);
}

// ---------------------------------------------------------------------------
// prep: hidden fp32 -> f16 ; W fp32 (K x N) -> Wt f16 (N x K) ; sincos table
// ---------------------------------------------------------------------------
__global__ __launch_bounds__(256) void prep_k(
    const float* __restrict__ hidden, const float* __restrict__ W,
    _Float16* __restrict__ Xb, _Float16* __restrict__ Wt,
    float2* __restrict__ tab)
{
  __shared__ float t_lds[32][33];
  const int b = blockIdx.x;
  const int t = threadIdx.x;
  if (b < 1152) {                     // W transpose: 24 (K/32) x 48 (N/32) tiles
    const int tk = b % 24, tn = b / 24;
    const int k0 = tk * 32, n0 = tn * 32;
    const int tx = t & 31, ty = t >> 5;
#pragma unroll
    for (int r = 0; r < 4; ++r)
      t_lds[ty + r * 8][tx] = W[(size_t)(k0 + ty + r * 8) * NOUT + n0 + tx];
    __syncthreads();
#pragma unroll
    for (int r = 0; r < 4; ++r)
      Wt[(size_t)(n0 + ty + r * 8) * HID + k0 + tx] = (_Float16)t_lds[tx][ty + r * 8];
  } else if (b < 1152 + 6144) {       // hidden convert: 1572864 float4s
    const int idx = (b - 1152) * 256 + t;
    float4 v = ((const float4*)hidden)[idx];
    f16x4 o;
    o.x = (_Float16)v.x; o.y = (_Float16)v.y;
    o.z = (_Float16)v.z; o.w = (_Float16)v.w;
    ((f16x4*)Xb)[idx] = o;
  } else {                            // sincos table: 512 pos x 32 freqs
    const int e = (b - 7296) * 256 + t;   // < 16384
    const int si = e >> 5, fi = e & 31;
    float inv = powf(10000.f, -(float)fi / 32.f);
    float ang = (float)si * inv;
    float sv, cv;
    sincosf(ang, &sv, &cv);
    tab[e] = make_float2(cv, sv);
  }
}

// ---------------------------------------------------------------------------
// GEMM1: Xb(8192x768) @ Wt^T -> +bias -> RoPE -> qb/kb f16 [b,h,s,64]
// 128x128 tile, BK=32, 4 waves, 4x4 frags of 16x16x32 f16 MFMA
// ---------------------------------------------------------------------------
__global__ __launch_bounds__(256) void gemm1_k(
    const _Float16* __restrict__ Xb, const _Float16* __restrict__ Wt,
    const float* __restrict__ bias, const float2* __restrict__ tab,
    _Float16* __restrict__ qb, _Float16* __restrict__ kb)
{
  __shared__ __align__(16) _Float16 As[128 * 32];
  __shared__ __align__(16) _Float16 Bs[128 * 32];
  const int tid = threadIdx.x;
  const int lane = tid & 63;
  const int m0 = blockIdx.x * 128;
  const int n0 = blockIdx.y * 128;
  const int wm = ((tid >> 6) & 1) * 64;
  const int wn = (tid >> 7) * 64;

  // staging: chunk s in {tid, tid+256}; row = s>>2, k-chunk = (s&3)*8
  const int s0r = tid >> 2, s0c = (tid & 3) * 8;
  const int s1r = (tid + 256) >> 2, s1c = (tid & 3) * 8;  // (tid+256)&3 == tid&3
  const _Float16* ag0 = Xb + (size_t)(m0 + s0r) * HID + s0c;
  const _Float16* ag1 = Xb + (size_t)(m0 + s1r) * HID + s1c;
  const _Float16* bg0 = Wt + (size_t)(n0 + s0r) * HID + s0c;
  const _Float16* bg1 = Wt + (size_t)(n0 + s1r) * HID + s1c;
  _Float16* al0 = &As[tid * 8];
  _Float16* al1 = &As[(tid + 256) * 8];
  _Float16* bl0 = &Bs[tid * 8];
  _Float16* bl1 = &Bs[(tid + 256) * 8];

  const int lrow = lane & 15;
  const int lk = (lane >> 4) * 8;

  f32x4 acc[4][4] = {};

  for (int kt = 0; kt < 24; ++kt) {
    async_ld16(ag0, al0);
    async_ld16(ag1, al1);
    async_ld16(bg0, bl0);
    async_ld16(bg1, bl1);
    ag0 += 32; ag1 += 32; bg0 += 32; bg1 += 32;
    __syncthreads();
    f16x8 af[4], bf[4];
#pragma unroll
    for (int i = 0; i < 4; ++i) {
      af[i] = *(const f16x8*)&As[(wm + i * 16 + lrow) * 32 + lk];
      bf[i] = *(const f16x8*)&Bs[(wn + i * 16 + lrow) * 32 + lk];
    }
#pragma unroll
    for (int i = 0; i < 4; ++i)
#pragma unroll
      for (int j = 0; j < 4; ++j)
        acc[i][j] = __builtin_amdgcn_mfma_f32_16x16x32_f16(af[i], bf[j], acc[i][j], 0, 0, 0);
    __syncthreads();
  }

  // epilogue: bias + interleaved RoPE (pair col n^1 == lane^1), store f16
  const int qlane = lane >> 4;
#pragma unroll
  for (int j = 0; j < 4; ++j) {
    const int n = n0 + wn + j * 16 + (lane & 15);
    const float bn = bias[n];
    const int d = n & 63;
    const int fi = d >> 1;
    const int h = n >> 7;
    _Float16* dst = ((n >> 6) & 1) ? kb : qb;
    const int odd = n & 1;
#pragma unroll
    for (int i = 0; i < 4; ++i) {
#pragma unroll
      for (int r = 0; r < 4; ++r) {
        const int m = m0 + wm + i * 16 + qlane * 4 + r;
        const int si = m & (SEQ - 1);
        const int bb = m >> 9;
        float val = acc[i][j][r] + bn;
        float pv = __shfl_xor(val, 1, 64);
        float2 cs = tab[si * 32 + fi];
        // even d: x*c - x[d+1]*s ; odd d: x*c + x[d-1]*s
        float o = odd ? fmaf(val, cs.x, pv * cs.y) : fmaf(val, cs.x, -pv * cs.y);
        dst[((size_t)(bb * HEADS + h) * SEQ + si) * HSZ + d] = (_Float16)o;
      }
    }
  }
}

// ---------------------------------------------------------------------------
// GEMM2: per (b,h): S = Q K^T (512x512x64), scale + causal/pad mask, fp32 out
// 128x128 tile; K staged as two packed [128][32] halves (global_load_lds safe)
// blocks fully below diagonal skip compute (|S/8| << threshold)
// ---------------------------------------------------------------------------
__global__ __launch_bounds__(256) void gemm2_k(
    const _Float16* __restrict__ qb, const _Float16* __restrict__ kb,
    const int* __restrict__ am, float* __restrict__ out)
{
  __shared__ __align__(16) _Float16 Qs[2 * 128 * 32];
  __shared__ __align__(16) _Float16 Ks[2 * 128 * 32];
  const int tid = threadIdx.x;
  const int bh = blockIdx.y;
  const int bb = bh / HEADS;
  const int mt = blockIdx.x >> 2, nt = blockIdx.x & 3;
  const int m0 = mt * 128, n0 = nt * 128;
  const int* amb = am + bb * SEQ;
  float* obase = out + (size_t)bh * SEQ * SEQ;

  if (nt < mt) {  // fully masked by tril(k=-1): write -(tri+pad)*NEG_BIG/8
#pragma unroll
    for (int q = 0; q < 16; ++q) {
      const int f = q * 256 + tid;
      const int row = f >> 5, c4 = (f & 31) * 4;
      const int m = m0 + row;
      const float amm = (float)amb[m];
      const int nb = n0 + c4;
      float4 v;
      v.x = -(2.f - amm * (float)amb[nb + 0]) * NEGQ;
      v.y = -(2.f - amm * (float)amb[nb + 1]) * NEGQ;
      v.z = -(2.f - amm * (float)amb[nb + 2]) * NEGQ;
      v.w = -(2.f - amm * (float)amb[nb + 3]) * NEGQ;
      *(float4*)&obase[(size_t)m * SEQ + nb] = v;
    }
    return;
  }

  const _Float16* qg = qb + (size_t)bh * SEQ * HSZ;
  const _Float16* kg = kb + (size_t)bh * SEQ * HSZ;
#pragma unroll
  for (int ct = 0; ct < 4; ++ct) {
    const int s = ct * 256 + tid;
    const int half = s >> 9, row = (s >> 2) & 127, c8 = (s & 3) * 8;
    async_ld16(qg + (size_t)(m0 + row) * HSZ + half * 32 + c8, &Qs[s * 8]);
    async_ld16(kg + (size_t)(n0 + row) * HSZ + half * 32 + c8, &Ks[s * 8]);
  }
  __syncthreads();

  const int lane = tid & 63;
  const int wm = ((tid >> 6) & 1) * 64;
  const int wn = (tid >> 7) * 64;
  const int lrow = lane & 15;
  const int lk = (lane >> 4) * 8;
  f32x4 acc[4][4] = {};
#pragma unroll
  for (int half = 0; half < 2; ++half) {
    f16x8 af[4], bf[4];
#pragma unroll
    for (int i = 0; i < 4; ++i) {
      af[i] = *(const f16x8*)&Qs[half * 4096 + (wm + i * 16 + lrow) * 32 + lk];
      bf[i] = *(const f16x8*)&Ks[half * 4096 + (wn + i * 16 + lrow) * 32 + lk];
    }
#pragma unroll
    for (int i = 0; i < 4; ++i)
#pragma unroll
      for (int j = 0; j < 4; ++j)
        acc[i][j] = __builtin_amdgcn_mfma_f32_16x16x32_f16(af[i], bf[j], acc[i][j], 0, 0, 0);
  }

  const int qlane = lane >> 4;
  int amm[4][4];
#pragma unroll
  for (int i = 0; i < 4; ++i)
#pragma unroll
    for (int r = 0; r < 4; ++r)
      amm[i][r] = amb[m0 + wm + i * 16 + qlane * 4 + r];

#pragma unroll
  for (int j = 0; j < 4; ++j) {
    const int n = n0 + wn + j * 16 + (lane & 15);
    const int amn = amb[n];
#pragma unroll
    for (int i = 0; i < 4; ++i) {
#pragma unroll
      for (int r = 0; r < 4; ++r) {
        const int m = m0 + wm + i * 16 + qlane * 4 + r;
        const float msk = (float)((int)(n < m) + (1 - amm[i][r] * amn));
        obase[(size_t)m * SEQ + n] = fmaf(acc[i][j][r], 0.125f, -msk * NEGQ);
      }
    }
  }
}

// ---------------------------------------------------------------------------
extern "C" void kernel_launch(void* const* d_in, const int* in_sizes, int n_in,
                              void* d_out, int out_size, void* d_ws, size_t ws_size,
                              hipStream_t stream) {
  const float* hidden = (const float*)d_in[0];
  const int*   am     = (const int*)d_in[1];
  const float* W      = (const float*)d_in[2];
  const float* bias   = (const float*)d_in[3];
  float* out = (float*)d_out;
  char* ws = (char*)d_ws;
  // workspace layout (all 16B-aligned): total 40,239,104 B
  _Float16* Xb = (_Float16*)(ws);               // 8192*768*2   = 12,582,912
  _Float16* Wt = (_Float16*)(ws + 12582912);    // 1536*768*2   =  2,359,296
  _Float16* qb = (_Float16*)(ws + 14942208);    // 16*12*512*64*2 = 12,582,912
  _Float16* kb = (_Float16*)(ws + 27525120);    // 12,582,912
  float2*   tab = (float2*)(ws + 40108032);     // 512*32*8 = 131,072

  prep_k<<<dim3(7360), dim3(256), 0, stream>>>(hidden, W, Xb, Wt, tab);
  gemm1_k<<<dim3(64, 12), dim3(256), 0, stream>>>(Xb, Wt, bias, tab, qb, kb);
  gemm2_k<<<dim3(16, 192), dim3(256), 0, stream>>>(qb, kb, am, out);
}